// Round 4
// baseline (6533.276 us; speedup 1.0000x reference)
//
#include <hip/hip_runtime.h>

typedef _Float16 half_t;
typedef half_t f16x8 __attribute__((ext_vector_type(8)));
typedef float  f32x4 __attribute__((ext_vector_type(4)));
typedef unsigned int u32;
typedef unsigned long long u64;
typedef unsigned short u16;

#define T_STEPS 256
#define NBG 32
#define D_RING 32   // ring depth in steps (power of 2)

#define L0_HALVES (16*4*10*512)                 // 327,680
#define L1_HALVES (16*4*16*512)                 // 524,288
#define WB_BYTES  ((L0_HALVES + L1_HALVES)*2)   // 1,703,936
#define RING_OFF  WB_BYTES
#define RING_BYTES (NBG * D_RING * 16 * 128 * 8)  // 2,097,152
#define PROG_OFF  (RING_OFF + RING_BYTES)
// ws total: PROG_OFF + NBG*64 = 3,803,136 bytes

__global__ void init_ws(u32* __restrict__ p) {
  int i = blockIdx.x * 1024 + threadIdx.x;
  if (i < (int)((RING_BYTES + NBG*64) / 4)) p[i] = 0;  // tag 0 != any want; prog 0 -> producer waits
}

// ---- pack fp32 weights into fp16 MFMA B-fragments, gate-interleaved cols ----
// col' = wave*64 + tile*16 + l15 ; unit = col'>>2, gate = col'&3 ; W-row = gate*256+unit
// k = kc*32 + (lane>>4)*8 + j  (16x16x32 f16 fragment k-mapping, verified rounds 1-3)
__global__ void pack_weights(const float* __restrict__ wih0, const float* __restrict__ whh0,
                             const float* __restrict__ wih1, const float* __restrict__ whh1,
                             half_t* __restrict__ wsB) {
  int idx = blockIdx.x * 256 + threadIdx.x;     // < 851,968
  int j    = idx & 7;
  int lane = (idx >> 3) & 63;
  float v;
  if (idx < L0_HALVES) {
    int rest = idx >> 9;                        // (wv*4+tile)*10 + kc
    int kc = rest % 10, wt = rest / 10;
    int colp = (wt >> 2) * 64 + (wt & 3) * 16 + (lane & 15);
    int wr = (colp & 3) * 256 + (colp >> 2);
    int k = kc * 32 + ((lane >> 4) << 3) + j;
    v = (k < 64) ? wih0[wr * 64 + k] : whh0[wr * 256 + k - 64];
  } else {
    int i1 = idx - L0_HALVES;
    int rest = i1 >> 9;                         // (wv*4+tile)*16 + kc
    int kc = rest & 15, wt = rest >> 4;
    int colp = (wt >> 2) * 64 + (wt & 3) * 16 + (lane & 15);
    int wr = (colp & 3) * 256 + (colp >> 2);
    int k = kc * 32 + ((lane >> 4) << 3) + j;
    v = (k < 256) ? wih1[wr * 256 + k] : whh1[wr * 256 + k - 256];
  }
  wsB[idx] = (half_t)v;
}

__device__ __forceinline__ float sigm(float x)   { return 1.0f / (1.0f + __expf(-x)); }
__device__ __forceinline__ float tanh_f(float x) { return 1.0f - 2.0f / (__expf(2.0f * x) + 1.0f); }
__device__ __forceinline__ float wsum(float v) {
  #pragma unroll
  for (int m = 1; m < 64; m <<= 1) v += __shfl_xor(v, m, 64);
  return v;
}
// A-fragment from swizzled LDS tile (byte ^= (row&7)<<4; row=l15, k=kc*32+l4*8+j)
__device__ __forceinline__ f16x8 ldA(const char* base, int stride, int kc, int l15, int l4) {
  int byo = l15 * stride + kc * 64 + l4 * 16;
  byo ^= (l15 & 7) << 4;
  return *(const f16x8*)(base + byo);
}
// In-wave 4x4 transpose across quad lanes: in a[r]=M[q][r] -> out a[g]=M[g][q]  (q=lane&3)
__device__ __forceinline__ void quad_transpose(float a[4], int lane) {
  float y0 = __shfl_xor(a[0], 1), y1 = __shfl_xor(a[1], 1),
        y2 = __shfl_xor(a[2], 1), y3 = __shfl_xor(a[3], 1);
  bool odd = (lane & 1);
  float c0 = odd ? y1 : a[0];
  float c1 = odd ? a[1] : y0;
  float c2 = odd ? y3 : a[2];
  float c3 = odd ? a[3] : y2;
  float z0 = __shfl_xor(c0, 2), z1 = __shfl_xor(c1, 2),
        z2 = __shfl_xor(c2, 2), z3 = __shfl_xor(c3, 2);
  bool hi = (lane & 2);
  a[0] = hi ? z2 : c0;
  a[1] = hi ? z3 : c1;
  a[2] = hi ? c2 : z0;
  a[3] = hi ? c3 : z1;
}

// 64 blocks x 1024 threads. Blocks 0..31: layer-0 producer (per bg); 32..63: layer-1 consumer.
// All weights in VGPRs; h-recurrences local in LDS; only h1 crosses blocks, one-directionally.
__global__ __launch_bounds__(1024, 4)
void lstm_pipe(const float* __restrict__ x,
               const float* __restrict__ bih0, const float* __restrict__ bhh0,
               const float* __restrict__ bih1, const float* __restrict__ bhh1,
               const float* __restrict__ gam, const float* __restrict__ bet,
               const float* __restrict__ headw, const float* __restrict__ headb,
               char* __restrict__ ws, float* __restrict__ out) {
  __shared__ __align__(16) char smem[16384];
  const int tid = threadIdx.x;
  const int wv = tid >> 6, lane = tid & 63;
  const int l15 = lane & 15, l4 = lane >> 4;
  const int q = lane & 3, s = l15 >> 2;
  const int crow = 4 * l4 + q;                 // cell-row owned by this lane (per tile)
  const half_t* wsB = (const half_t*)ws;
  u64* ring = (u64*)(ws + RING_OFF);

  if (blockIdx.x < NBG) {
    // ================= L0: layer-0 producer =================
    const int bg = blockIdx.x;
    char* xt  = smem;                          // [16][64]  f16, stride 128B, swizzled
    char* h1t = smem + 2048;                   // [16][256] f16, stride 512B, swizzled
    u64* ringbg = ring + (size_t)bg * (D_RING * 16 * 128);
    int* progp = (int*)(ws + PROG_OFF + bg * 64);

    f16x8 W0[40];
    { const f16x8* wp = (const f16x8*)wsB;
      #pragma unroll
      for (int i = 0; i < 40; i++) W0[i] = wp[(wv * 40 + i) * 64 + lane]; }
    float bv[4][4];
    #pragma unroll
    for (int tile = 0; tile < 4; tile++) {
      int u = wv * 16 + tile * 4 + s;
      #pragma unroll
      for (int g = 0; g < 4; g++) bv[tile][g] = bih0[g * 256 + u] + bhh0[g * 256 + u];
    }
    for (int i = tid; i < 2048; i += 1024) ((u32*)h1t)[i] = 0;
    { float xv = x[((size_t)(bg * 16 + wv) * T_STEPS + 0) * 64 + lane];
      int bo = wv * 128 + lane * 2; bo ^= (wv & 7) << 4;
      *(half_t*)(xt + bo) = (half_t)xv; }
    float c0[4] = {0.f, 0.f, 0.f, 0.f};
    int prog_c = -0x40000000;

    for (int t = 0; t < T_STEPS; t++) {
      float xnext = 0.f;
      if (t + 1 < T_STEPS)
        xnext = x[((size_t)(bg * 16 + wv) * T_STEPS + (t + 1)) * 64 + lane];
      __syncthreads();                          // B1: staged writes visible

      f32x4 acc[4] = {};
      #pragma unroll
      for (int kc = 0; kc < 10; kc++) {
        f16x8 a = (kc < 2) ? ldA(xt, 128, kc, l15, l4) : ldA(h1t, 512, kc - 2, l15, l4);
        #pragma unroll
        for (int tile = 0; tile < 4; tile++)
          acc[tile] = __builtin_amdgcn_mfma_f32_16x16x32_f16(a, W0[tile * 10 + kc], acc[tile], 0, 0, 0);
      }
      u32 hbits[4];
      #pragma unroll
      for (int tile = 0; tile < 4; tile++) {
        float g4[4] = {acc[tile][0], acc[tile][1], acc[tile][2], acc[tile][3]};
        quad_transpose(g4, lane);               // g4[g] now gates i,f,g,o for (crow, unit)
        float gi = g4[0] + bv[tile][0], gf = g4[1] + bv[tile][1];
        float gg = g4[2] + bv[tile][2], go = g4[3] + bv[tile][3];
        c0[tile] = sigm(gf) * c0[tile] + sigm(gi) * tanh_f(gg);
        float h = sigm(go) * tanh_f(c0[tile]);
        union { half_t hf; u16 us; } cv; cv.hf = (half_t)h;
        hbits[tile] = cv.us;
      }
      // back-pressure: only if wrapping onto a slot the consumer may not have read
      if (tid == 0 && t >= D_RING) {
        while (prog_c < t - (D_RING - 1)) {
          prog_c = __hip_atomic_load(progp, __ATOMIC_RELAXED, __HIP_MEMORY_SCOPE_AGENT);
          if (prog_c < t - (D_RING - 1)) __builtin_amdgcn_s_sleep(2);
        }
      }
      __syncthreads();                          // B2: all MM reads done
      #pragma unroll
      for (int tile = 0; tile < 4; tile++) {
        int unit = wv * 16 + tile * 4 + s;
        int bo = crow * 512 + unit * 2; bo ^= (crow & 7) << 4;
        *(u16*)(h1t + bo) = (u16)hbits[tile];
        u32 pb = (u32)__shfl_xor((int)hbits[tile], 4);   // partner unit (s^1)
        if (!(s & 1)) {                         // even-unit lanes publish the pair
          u32 pair = hbits[tile] | (pb << 16);
          u64 word = (u64)(u32)(t + 1) | ((u64)pair << 32);
          int p = wv * 8 + tile * 2 + (s >> 1);
          __hip_atomic_store(&ringbg[((size_t)(t & (D_RING - 1)) * 16 + crow) * 128 + p],
                             word, __ATOMIC_RELAXED, __HIP_MEMORY_SCOPE_AGENT);
        }
      }
      if (t + 1 < T_STEPS) {
        int bo = wv * 128 + lane * 2; bo ^= (wv & 7) << 4;
        *(half_t*)(xt + bo) = (half_t)xnext;
      }
    }
    return;
  }

  // ================= L1: layer-1 consumer + LN/GELU/head =================
  const int bg = blockIdx.x - NBG;
  char* h1t = smem;                             // [16][256] f16, stride 512B, swizzled
  char* h2t = smem + 8192;
  float* HF = (float*)smem;                     // f32 [16][256] overlay at final step
  u64* ringbg = ring + (size_t)bg * (D_RING * 16 * 128);
  int* progp = (int*)(ws + PROG_OFF + bg * 64);

  f16x8 W1[64];
  { const f16x8* wp = (const f16x8*)wsB + (L0_HALVES / 8);
    #pragma unroll
    for (int i = 0; i < 64; i++) W1[i] = wp[(wv * 64 + i) * 64 + lane]; }
  float bv[4][4];
  #pragma unroll
  for (int tile = 0; tile < 4; tile++) {
    int u = wv * 16 + tile * 4 + s;
    #pragma unroll
    for (int g = 0; g < 4; g++) bv[tile][g] = bih1[g * 256 + u] + bhh1[g * 256 + u];
  }
  for (int i = tid; i < 2048; i += 1024) ((u32*)h2t)[i] = 0;
  float c1[4] = {0.f, 0.f, 0.f, 0.f};

  const int P0 = tid, P1 = tid + 1024;
  const int r0 = P0 >> 7, p0 = P0 & 127, r1 = P1 >> 7, p1 = P1 & 127;
  u64 pw0 = __hip_atomic_load(&ringbg[(size_t)(0 * 16 + r0) * 128 + p0], __ATOMIC_RELAXED, __HIP_MEMORY_SCOPE_AGENT);
  u64 pw1 = __hip_atomic_load(&ringbg[(size_t)(0 * 16 + r1) * 128 + p1], __ATOMIC_RELAXED, __HIP_MEMORY_SCOPE_AGENT);

  for (int t = 0; t < T_STEPS; t++) {
    const u32 want = (u32)(t + 1);
    const size_t slot = (size_t)(t & (D_RING - 1));
    for (;;) {                                  // usually hits first try (prefetched)
      if ((u32)pw0 == want && (u32)pw1 == want) break;
      __builtin_amdgcn_s_sleep(2);
      pw0 = __hip_atomic_load(&ringbg[(slot * 16 + r0) * 128 + p0], __ATOMIC_RELAXED, __HIP_MEMORY_SCOPE_AGENT);
      pw1 = __hip_atomic_load(&ringbg[(slot * 16 + r1) * 128 + p1], __ATOMIC_RELAXED, __HIP_MEMORY_SCOPE_AGENT);
    }
    { int bo = r0 * 512 + p0 * 4; bo ^= (r0 & 7) << 4; *(u32*)(h1t + bo) = (u32)(pw0 >> 32); }
    { int bo = r1 * 512 + p1 * 4; bo ^= (r1 & 7) << 4; *(u32*)(h1t + bo) = (u32)(pw1 >> 32); }
    if (t + 1 < T_STEPS) {                      // prefetch next step's words
      size_t ns = (size_t)((t + 1) & (D_RING - 1));
      pw0 = __hip_atomic_load(&ringbg[(ns * 16 + r0) * 128 + p0], __ATOMIC_RELAXED, __HIP_MEMORY_SCOPE_AGENT);
      pw1 = __hip_atomic_load(&ringbg[(ns * 16 + r1) * 128 + p1], __ATOMIC_RELAXED, __HIP_MEMORY_SCOPE_AGENT);
    }
    __syncthreads();                            // B1: h1[t] staged, all threads consumed slot
    if (tid == 0)                               // safe only after B1 (all threads past poll)
      __hip_atomic_store(progp, t + 1, __ATOMIC_RELAXED, __HIP_MEMORY_SCOPE_AGENT);

    f32x4 acc[4] = {};
    #pragma unroll
    for (int kc = 0; kc < 16; kc++) {
      f16x8 a = (kc < 8) ? ldA(h1t, 512, kc, l15, l4) : ldA(h2t, 512, kc - 8, l15, l4);
      #pragma unroll
      for (int tile = 0; tile < 4; tile++)
        acc[tile] = __builtin_amdgcn_mfma_f32_16x16x32_f16(a, W1[tile * 16 + kc], acc[tile], 0, 0, 0);
    }
    u32 hbits[4]; float hfl[4];
    #pragma unroll
    for (int tile = 0; tile < 4; tile++) {
      float g4[4] = {acc[tile][0], acc[tile][1], acc[tile][2], acc[tile][3]};
      quad_transpose(g4, lane);
      float gi = g4[0] + bv[tile][0], gf = g4[1] + bv[tile][1];
      float gg = g4[2] + bv[tile][2], go = g4[3] + bv[tile][3];
      c1[tile] = sigm(gf) * c1[tile] + sigm(gi) * tanh_f(gg);
      float h = sigm(go) * tanh_f(c1[tile]);
      hfl[tile] = h;
      union { half_t hf; u16 us; } cv; cv.hf = (half_t)h;
      hbits[tile] = cv.us;
    }
    __syncthreads();                            // B2: all MM reads done
    if (t + 1 < T_STEPS) {
      #pragma unroll
      for (int tile = 0; tile < 4; tile++) {
        int unit = wv * 16 + tile * 4 + s;
        int bo = crow * 512 + unit * 2; bo ^= (crow & 7) << 4;
        *(u16*)(h2t + bo) = (u16)hbits[tile];
      }
    } else {
      #pragma unroll
      for (int tile = 0; tile < 4; tile++) {
        int unit = wv * 16 + tile * 4 + s;
        HF[crow * 256 + unit] = hfl[tile];      // f32 final h2 (overlays dead h1t/h2t)
      }
    }
  }
  __syncthreads();

  // ---- LayerNorm + exact GELU + head; wave wv owns batch-row wv ----
  float vv[4], sm = 0.f;
  #pragma unroll
  for (int qq = 0; qq < 4; qq++) { vv[qq] = HF[wv * 256 + qq * 64 + lane]; sm += vv[qq]; }
  sm = wsum(sm);
  float mu = sm * (1.0f / 256.0f);
  float vs = 0.f;
  #pragma unroll
  for (int qq = 0; qq < 4; qq++) { float d = vv[qq] - mu; vs += d * d; }
  vs = wsum(vs);
  float rstd = rsqrtf(vs * (1.0f / 256.0f) + 1e-5f);
  float dot = 0.f;
  #pragma unroll
  for (int qq = 0; qq < 4; qq++) {
    int uu = qq * 64 + lane;
    float y = (vv[qq] - mu) * rstd * gam[uu] + bet[uu];
    float ge = 0.5f * y * (1.0f + erff(y * 0.70710678118f));
    dot += ge * headw[uu];
  }
  dot = wsum(dot);
  if (lane == 0) out[bg * 16 + wv] = dot + headb[0];
}

extern "C" void kernel_launch(void* const* d_in, const int* in_sizes, int n_in,
                              void* d_out, int out_size, void* d_ws, size_t ws_size,
                              hipStream_t stream) {
  const float* x    = (const float*)d_in[0];
  const float* wih0 = (const float*)d_in[1];
  const float* whh0 = (const float*)d_in[2];
  const float* bih0 = (const float*)d_in[3];
  const float* bhh0 = (const float*)d_in[4];
  const float* wih1 = (const float*)d_in[5];
  const float* whh1 = (const float*)d_in[6];
  const float* bih1 = (const float*)d_in[7];
  const float* bhh1 = (const float*)d_in[8];
  const float* gam  = (const float*)d_in[9];
  const float* bet  = (const float*)d_in[10];
  const float* hw   = (const float*)d_in[11];
  const float* hb   = (const float*)d_in[12];
  char* ws = (char*)d_ws;  // needs 3,803,136 bytes

  hipLaunchKernelGGL(init_ws, dim3(((RING_BYTES + NBG*64)/4 + 1023) / 1024), dim3(1024), 0, stream,
                     (u32*)(ws + RING_OFF));
  hipLaunchKernelGGL(pack_weights, dim3(3328), dim3(256), 0, stream,
                     wih0, whh0, wih1, whh1, (half_t*)ws);
  hipLaunchKernelGGL(lstm_pipe, dim3(64), dim3(1024), 0, stream,
                     x, bih0, bhh0, bih1, bhh1, gam, bet, hw, hb, ws, (float*)d_out);
}

// Round 5
// 4738.852 us; speedup vs baseline: 1.3787x; 1.3787x over previous
//
#include <hip/hip_runtime.h>

typedef _Float16 half_t;
typedef half_t f16x8 __attribute__((ext_vector_type(8)));
typedef float  f32x4 __attribute__((ext_vector_type(4)));
typedef unsigned int u32;
typedef unsigned long long u64;
typedef unsigned short u16;

#define T_STEPS 256
#define NBG 32
#define NHG 16
#define DSLOT 2

#define WB_HALVES (NHG*4*26*512)          // 851,968
#define WB_BYTES  (WB_HALVES*2)           // 1,703,936
#define RING_OFF  WB_BYTES
#define RING_WORDS (DSLOT*NBG*4096)       // 262,144 u64 = 2 MiB
// ws total = 3,801,088 bytes (same footprint as round 4)

__global__ void init_ws(u32* __restrict__ p) {
  int i = blockIdx.x * 1024 + threadIdx.x;
  if (i < RING_WORDS * 2) p[i] = 0;       // tag 0 < any want (wants start at 1)
}

// ---- pack fp32 weights into fp16 MFMA B-fragments, gate-interleaved ----
// Layout: [hg 16][wv 4][kc 26][lane 64][8 halves]; kc 0..9 layer0 (K=320), 10..25 layer1 (K=512).
// Wave (hg,wv) cols: colp = wv*16 + (lane&15) in [0,64) -> unit_local = colp>>2, gate = colp&3;
// W-row = gate*256 + hg*16 + unit_local (PyTorch i,f,g,o). k = kc*32 + (lane>>4)*8 + j.
__global__ void pack_weights(const float* __restrict__ wih0, const float* __restrict__ whh0,
                             const float* __restrict__ wih1, const float* __restrict__ whh1,
                             half_t* __restrict__ wsB) {
  int idx = blockIdx.x * 256 + threadIdx.x;       // < 851,968
  int j    = idx & 7;
  int lane = (idx >> 3) & 63;
  int kc   = (idx >> 9) % 26;
  int sl   = (idx >> 9) / 26;                     // hg*4 + wv
  int hg = sl >> 2, wv = sl & 3;
  int colp = wv * 16 + (lane & 15);
  int wr = (colp & 3) * 256 + hg * 16 + (colp >> 2);
  int kf = ((lane >> 4) << 3) + j;
  float v;
  if (kc < 10) { int kk = kc * 32 + kf;        v = (kk < 64)  ? wih0[wr * 64 + kk]  : whh0[wr * 256 + kk - 64]; }
  else         { int kk = (kc - 10) * 32 + kf; v = (kk < 256) ? wih1[wr * 256 + kk] : whh1[wr * 256 + kk - 256]; }
  wsB[idx] = (half_t)v;
}

__device__ __forceinline__ float sigm(float x)   { return 1.0f / (1.0f + __expf(-x)); }
__device__ __forceinline__ float tanh_f(float x) { return 1.0f - 2.0f / (__expf(2.0f * x) + 1.0f); }
__device__ __forceinline__ float wsum(float v) {
  #pragma unroll
  for (int m = 1; m < 64; m <<= 1) v += __shfl_xor(v, m, 64);
  return v;
}
// A-fragment from swizzled LDS tile (byte ^= (row&7)<<4; row = l15, k = kc*32 + l4*8 + j)
__device__ __forceinline__ f16x8 ldA(const char* base, int stride, int kc, int l15, int l4) {
  int byo = l15 * stride + kc * 64 + l4 * 16;
  byo ^= (l15 & 7) << 4;
  return *(const f16x8*)(base + byo);
}
// In-wave 4x4 transpose across quad lanes (verified round 4): a[r]=M[q][r] -> a[g]=M[g][q], q=lane&3
__device__ __forceinline__ void quad_transpose(float a[4], int lane) {
  float y0 = __shfl_xor(a[0], 1), y1 = __shfl_xor(a[1], 1),
        y2 = __shfl_xor(a[2], 1), y3 = __shfl_xor(a[3], 1);
  bool odd = (lane & 1);
  float c0v = odd ? y1 : a[0];
  float c1v = odd ? a[1] : y0;
  float c2v = odd ? y3 : a[2];
  float c3v = odd ? a[3] : y2;
  float z0 = __shfl_xor(c0v, 2), z1 = __shfl_xor(c1v, 2),
        z2 = __shfl_xor(c2v, 2), z3 = __shfl_xor(c3v, 2);
  bool hi = (lane & 2);
  a[0] = hi ? z2 : c0v;
  a[1] = hi ? z3 : c1v;
  a[2] = hi ? c2v : z0;
  a[3] = hi ? c3v : z1;
}

// 512 blocks x 256 threads (4 waves). Block (bg,hg): 16 batch rows x 16 units (4 gates each).
// bid = bg*16 + hg  ->  co-resident sibling (bid+256) is a DIFFERENT bg: stall hiding on-CU.
// Weights in regs; h1/h2 exchanged once per step via tagged u64 words (tag+payload atomic).
__global__ __launch_bounds__(256, 2)
void lstm_fused(const float* __restrict__ x,
                const float* __restrict__ bih0, const float* __restrict__ bhh0,
                const float* __restrict__ bih1, const float* __restrict__ bhh1,
                const float* __restrict__ gam, const float* __restrict__ bet,
                const float* __restrict__ headw, const float* __restrict__ headb,
                char* __restrict__ ws, float* __restrict__ out) {
  __shared__ __align__(16) char smem[18432];
  char* XT = smem;          // [16][64]  f16, stride 128B, swizzled
  char* H1 = smem + 2048;   // [16][256] f16, stride 512B, swizzled
  char* H2 = smem + 10240;  // [16][256] f16, stride 512B, swizzled

  const int tid = threadIdx.x;
  const int wv = tid >> 6, lane = tid & 63;
  const int l15 = lane & 15, l4 = lane >> 4;
  const int q = lane & 3, s = l15 >> 2;
  const int crow = l4 * 4 + q;            // cell row owned by this lane
  const int ul = wv * 4 + s;              // local unit owned by this lane
  const int bg = blockIdx.x >> 4, hg = blockIdx.x & 15;
  const int gr = tid >> 4, gu0 = (tid & 15) * 16;   // gather/stage mapping

  const half_t* wsB = (const half_t*)ws;
  u64* ring = (u64*)(ws + RING_OFF);

  // ---- weights -> registers (26 frags = 104 regs/lane) ----
  f16x8 B0r[10], B1r[16];
  { const f16x8* wp = (const f16x8*)wsB + (size_t)((hg * 4 + wv) * 26) * 64 + lane;
    #pragma unroll
    for (int f = 0; f < 10; f++) B0r[f] = wp[f * 64];
    #pragma unroll
    for (int f = 0; f < 16; f++) B1r[f] = wp[(10 + f) * 64]; }

  float bv0[4], bv1[4];
  { int ug = hg * 16 + ul;
    #pragma unroll
    for (int g = 0; g < 4; g++) {
      bv0[g] = bih0[g * 256 + ug] + bhh0[g * 256 + ug];
      bv1[g] = bih1[g * 256 + ug] + bhh1[g * 256 + ug];
    } }
  float c0 = 0.f, c1 = 0.f;
  const int pubidx = crow * 256 + hg * 16 + ul;

  // ---- prologue: zero H1 (h1[-1]=0), stage x0 ----
  for (int i2 = tid; i2 < 2048; i2 += 256) ((u32*)H1)[i2] = 0;
  { float4 v = *(const float4*)(x + ((size_t)(bg * 16 + gr) * T_STEPS + 0) * 64 + (tid & 15) * 4);
    union { half_t h[4]; u64 u; } cv;
    cv.h[0] = (half_t)v.x; cv.h[1] = (half_t)v.y; cv.h[2] = (half_t)v.z; cv.h[3] = (half_t)v.w;
    int bo = gr * 128 + (tid & 15) * 8; bo ^= (gr & 7) << 4;
    *(u64*)(XT + bo) = cv.u; }
  __syncthreads();

  // ---- proto: MM0(0) -> h1[0]; publish tag 1 = {h1[0], h2[-1]=0} ----
  {
    f32x4 acc0 = {0.f, 0.f, 0.f, 0.f};
    #pragma unroll
    for (int kc = 0; kc < 2; kc++)
      acc0 = __builtin_amdgcn_mfma_f32_16x16x32_f16(ldA(XT, 128, kc, l15, l4), B0r[kc], acc0, 0, 0, 0);
    #pragma unroll
    for (int kh = 0; kh < 8; kh++)
      acc0 = __builtin_amdgcn_mfma_f32_16x16x32_f16(ldA(H1, 512, kh, l15, l4), B0r[kh + 2], acc0, 0, 0, 0);
    float g0[4] = {acc0[0], acc0[1], acc0[2], acc0[3]};
    quad_transpose(g0, lane);
    c0 = sigm(g0[1] + bv0[1]) * c0 + sigm(g0[0] + bv0[0]) * tanh_f(g0[2] + bv0[2]);
    float h1f = sigm(g0[3] + bv0[3]) * tanh_f(c0);
    union { half_t hf; u16 us; } cv; cv.hf = (half_t)h1f;
    u64* ringS = ring + ((size_t)(1 & (DSLOT - 1)) * NBG + bg) * 4096;
    u64 word = (u64)1u | ((u64)(u32)cv.us << 32);
    __hip_atomic_store(&ringS[pubidx], word, __ATOMIC_RELAXED, __HIP_MEMORY_SCOPE_AGENT);
    asm volatile("s_waitcnt vmcnt(0)" ::: "memory");
  }

  // ---- main loop: iter i consumes tag i+1 = {h1[i], h2[i-1]}, publishes tag i+2 ----
  for (int i = 0; i < T_STEPS - 1; i++) {
    const u32 want = (u32)(i + 1);
    { // gather + stage H1/H2
      u64* src = ring + ((size_t)(want & (DSLOT - 1)) * NBG + bg) * 4096 + gr * 256 + gu0;
      u64 v[16];
      for (;;) {
        bool ok = true;
        #pragma unroll
        for (int k = 0; k < 16; k++) {
          v[k] = __hip_atomic_load(&src[k], __ATOMIC_RELAXED, __HIP_MEMORY_SCOPE_AGENT);
          ok &= ((u32)v[k] == want);
        }
        if (ok) break;
        __builtin_amdgcn_s_sleep(1);
      }
      union { u16 us[16]; uint4 u4[2]; } a1, a2;
      #pragma unroll
      for (int k = 0; k < 16; k++) { a1.us[k] = (u16)(v[k] >> 32); a2.us[k] = (u16)(v[k] >> 48); }
      int bo = gr * 512 + gu0 * 2; const int sw = (gr & 7) << 4;
      *(uint4*)(H1 + ((bo) ^ sw)) = a1.u4[0];
      *(uint4*)(H1 + ((bo + 16) ^ sw)) = a1.u4[1];
      *(uint4*)(H2 + ((bo) ^ sw)) = a2.u4[0];
      *(uint4*)(H2 + ((bo + 16) ^ sw)) = a2.u4[1];
    }
    { // stage x[i+1]
      float4 v = *(const float4*)(x + ((size_t)(bg * 16 + gr) * T_STEPS + (i + 1)) * 64 + (tid & 15) * 4);
      union { half_t h[4]; u64 u; } cv;
      cv.h[0] = (half_t)v.x; cv.h[1] = (half_t)v.y; cv.h[2] = (half_t)v.z; cv.h[3] = (half_t)v.w;
      int bo = gr * 128 + (tid & 15) * 8; bo ^= (gr & 7) << 4;
      *(u64*)(XT + bo) = cv.u;
    }
    __syncthreads();  // staged tiles visible to all waves

    // MM0 = [x[i+1] | h1[i]] @ W0^T ; MM1 = [h1[i] | h2[i-1]] @ W1^T  (H1 frags read once)
    f32x4 acc0 = {0.f, 0.f, 0.f, 0.f}, acc1 = {0.f, 0.f, 0.f, 0.f};
    #pragma unroll
    for (int kc = 0; kc < 2; kc++)
      acc0 = __builtin_amdgcn_mfma_f32_16x16x32_f16(ldA(XT, 128, kc, l15, l4), B0r[kc], acc0, 0, 0, 0);
    #pragma unroll
    for (int kh = 0; kh < 8; kh++) {
      f16x8 a = ldA(H1, 512, kh, l15, l4);
      acc0 = __builtin_amdgcn_mfma_f32_16x16x32_f16(a, B0r[kh + 2], acc0, 0, 0, 0);
      acc1 = __builtin_amdgcn_mfma_f32_16x16x32_f16(a, B1r[kh], acc1, 0, 0, 0);
    }
    #pragma unroll
    for (int kh = 0; kh < 8; kh++)
      acc1 = __builtin_amdgcn_mfma_f32_16x16x32_f16(ldA(H2, 512, kh, l15, l4), B1r[kh + 8], acc1, 0, 0, 0);

    // cells (lane-local after quad transpose)
    float g0[4] = {acc0[0], acc0[1], acc0[2], acc0[3]};
    quad_transpose(g0, lane);
    c0 = sigm(g0[1] + bv0[1]) * c0 + sigm(g0[0] + bv0[0]) * tanh_f(g0[2] + bv0[2]);
    float h1f = sigm(g0[3] + bv0[3]) * tanh_f(c0);
    float g1[4] = {acc1[0], acc1[1], acc1[2], acc1[3]};
    quad_transpose(g1, lane);
    c1 = sigm(g1[1] + bv1[1]) * c1 + sigm(g1[0] + bv1[0]) * tanh_f(g1[2] + bv1[2]);
    float h2f = sigm(g1[3] + bv1[3]) * tanh_f(c1);

    { // publish tag i+2 = {h1[i+1], h2[i]}
      union { half_t hf; u16 us; } cv1, cv2;
      cv1.hf = (half_t)h1f; cv2.hf = (half_t)h2f;
      const u32 tag2 = (u32)(i + 2);
      u64* ringP = ring + ((size_t)(tag2 & (DSLOT - 1)) * NBG + bg) * 4096;
      u64 word = (u64)tag2 | ((u64)((u32)cv1.us | ((u32)cv2.us << 16)) << 32);
      __hip_atomic_store(&ringP[pubidx], word, __ATOMIC_RELAXED, __HIP_MEMORY_SCOPE_AGENT);
      asm volatile("s_waitcnt vmcnt(0)" ::: "memory");
    }
    __syncthreads();  // all MM reads done before next iter's staging
  }

  // ---- epilogue: consume tag T = {h1[T-1], h2[T-2]}; MM1 only -> h2[T-1]; publish f32 tag T+1 ----
  {
    const u32 want = (u32)T_STEPS;
    u64* src = ring + ((size_t)(want & (DSLOT - 1)) * NBG + bg) * 4096 + gr * 256 + gu0;
    u64 v[16];
    for (;;) {
      bool ok = true;
      #pragma unroll
      for (int k = 0; k < 16; k++) {
        v[k] = __hip_atomic_load(&src[k], __ATOMIC_RELAXED, __HIP_MEMORY_SCOPE_AGENT);
        ok &= ((u32)v[k] == want);
      }
      if (ok) break;
      __builtin_amdgcn_s_sleep(1);
    }
    union { u16 us[16]; uint4 u4[2]; } a1, a2;
    #pragma unroll
    for (int k = 0; k < 16; k++) { a1.us[k] = (u16)(v[k] >> 32); a2.us[k] = (u16)(v[k] >> 48); }
    int bo = gr * 512 + gu0 * 2; const int sw = (gr & 7) << 4;
    *(uint4*)(H1 + ((bo) ^ sw)) = a1.u4[0];
    *(uint4*)(H1 + ((bo + 16) ^ sw)) = a1.u4[1];
    *(uint4*)(H2 + ((bo) ^ sw)) = a2.u4[0];
    *(uint4*)(H2 + ((bo + 16) ^ sw)) = a2.u4[1];
  }
  __syncthreads();
  {
    f32x4 acc1 = {0.f, 0.f, 0.f, 0.f};
    #pragma unroll
    for (int kh = 0; kh < 8; kh++) {
      f16x8 a = ldA(H1, 512, kh, l15, l4);
      acc1 = __builtin_amdgcn_mfma_f32_16x16x32_f16(a, B1r[kh], acc1, 0, 0, 0);
    }
    #pragma unroll
    for (int kh = 0; kh < 8; kh++)
      acc1 = __builtin_amdgcn_mfma_f32_16x16x32_f16(ldA(H2, 512, kh, l15, l4), B1r[kh + 8], acc1, 0, 0, 0);
    float g1[4] = {acc1[0], acc1[1], acc1[2], acc1[3]};
    quad_transpose(g1, lane);
    c1 = sigm(g1[1] + bv1[1]) * c1 + sigm(g1[0] + bv1[0]) * tanh_f(g1[2] + bv1[2]);
    float h2f = sigm(g1[3] + bv1[3]) * tanh_f(c1);
    const u32 tagF = (u32)(T_STEPS + 1);
    u64* ringP = ring + ((size_t)(tagF & (DSLOT - 1)) * NBG + bg) * 4096;
    u64 word = (u64)tagF | ((u64)__float_as_uint(h2f) << 32);
    __hip_atomic_store(&ringP[pubidx], word, __ATOMIC_RELAXED, __HIP_MEMORY_SCOPE_AGENT);
    asm volatile("s_waitcnt vmcnt(0)" ::: "memory");
  }
  if (hg != 0) return;

  // ---- LN + exact GELU + head (hg==0 blocks, one per bg) ----
  __syncthreads();
  float* HF = (float*)smem;  // [16][256] f32 overlay (tiles dead)
  {
    const u32 want = (u32)(T_STEPS + 1);
    u64* src = ring + ((size_t)(want & (DSLOT - 1)) * NBG + bg) * 4096 + gr * 256 + gu0;
    u64 v[16];
    for (;;) {
      bool ok = true;
      #pragma unroll
      for (int k = 0; k < 16; k++) {
        v[k] = __hip_atomic_load(&src[k], __ATOMIC_RELAXED, __HIP_MEMORY_SCOPE_AGENT);
        ok &= ((u32)v[k] == want);
      }
      if (ok) break;
      __builtin_amdgcn_s_sleep(1);
    }
    #pragma unroll
    for (int k = 0; k < 16; k++) HF[gr * 256 + gu0 + k] = __uint_as_float((u32)(v[k] >> 32));
  }
  __syncthreads();

  float hbv = headb[0];
  #pragma unroll
  for (int rj = 0; rj < 4; rj++) {
    int rr = wv * 4 + rj;
    float vv[4], sm = 0.f;
    #pragma unroll
    for (int qq = 0; qq < 4; qq++) { vv[qq] = HF[rr * 256 + qq * 64 + lane]; sm += vv[qq]; }
    sm = wsum(sm);
    float mu = sm * (1.0f / 256.0f);
    float vs = 0.f;
    #pragma unroll
    for (int qq = 0; qq < 4; qq++) { float d = vv[qq] - mu; vs += d * d; }
    vs = wsum(vs);
    float rstd = rsqrtf(vs * (1.0f / 256.0f) + 1e-5f);
    float dot = 0.f;
    #pragma unroll
    for (int qq = 0; qq < 4; qq++) {
      int uu = qq * 64 + lane;
      float y = (vv[qq] - mu) * rstd * gam[uu] + bet[uu];
      float ge = 0.5f * y * (1.0f + erff(y * 0.70710678118f));
      dot += ge * headw[uu];
    }
    dot = wsum(dot);
    if (lane == 0) out[bg * 16 + rr] = dot + hbv;
  }
}

extern "C" void kernel_launch(void* const* d_in, const int* in_sizes, int n_in,
                              void* d_out, int out_size, void* d_ws, size_t ws_size,
                              hipStream_t stream) {
  const float* x    = (const float*)d_in[0];
  const float* wih0 = (const float*)d_in[1];
  const float* whh0 = (const float*)d_in[2];
  const float* bih0 = (const float*)d_in[3];
  const float* bhh0 = (const float*)d_in[4];
  const float* wih1 = (const float*)d_in[5];
  const float* whh1 = (const float*)d_in[6];
  const float* bih1 = (const float*)d_in[7];
  const float* bhh1 = (const float*)d_in[8];
  const float* gam  = (const float*)d_in[9];
  const float* bet  = (const float*)d_in[10];
  const float* hw   = (const float*)d_in[11];
  const float* hb   = (const float*)d_in[12];
  char* ws = (char*)d_ws;  // needs 3,801,088 bytes

  hipLaunchKernelGGL(init_ws, dim3((RING_WORDS * 2 + 1023) / 1024), dim3(1024), 0, stream,
                     (u32*)(ws + RING_OFF));
  hipLaunchKernelGGL(pack_weights, dim3(3328), dim3(256), 0, stream,
                     wih0, whh0, wih1, whh1, (half_t*)ws);
  hipLaunchKernelGGL(lstm_fused, dim3(512), dim3(256), 0, stream,
                     x, bih0, bhh0, bih1, bhh1, gam, bet, hw, hb, ws, (float*)d_out);
}

// Round 6
// 1170.025 us; speedup vs baseline: 5.5839x; 4.0502x over previous
//
#include <hip/hip_runtime.h>

typedef _Float16 half_t;
typedef half_t f16x8 __attribute__((ext_vector_type(8)));
typedef float  f32x4 __attribute__((ext_vector_type(4)));
typedef unsigned int u32;
typedef unsigned long long u64;
typedef unsigned short u16;

#define T_STEPS 256
#define NBG 32
#define NHG 8
#define DSLOT 2

#define WB_HALVES (NHG*8*26*512)            // 851,968
#define WB_BYTES  (WB_HALVES*2)             // 1,703,936
#define RING_OFF  WB_BYTES
#define RING_WORDS (DSLOT*NBG*NHG*512)      // 262,144 u64 = 2 MiB
// ws total = 3,801,088 bytes

__global__ void init_ws(u32* __restrict__ p) {
  int i = blockIdx.x * 1024 + threadIdx.x;
  if (i < RING_WORDS * 2) p[i] = 0;         // tag 0 < smallest want (1)
}

// ---- pack fp32 weights into fp16 MFMA B-fragments, gate-interleaved cols ----
// Layout: [hg 8][w 8][kc 26][lane 64][8 halves]; kc 0..9 layer0 (K=320), 10..25 layer1 (K=512)
// Wave (hg,w), tile col c16 = lane&15: gate = c16&3, unit = hg*32 + w*4 + (c16>>2)
// W-row = gate*256 + unit (PyTorch i,f,g,o).  k = kc*32 + (lane>>4)*8 + j.
__global__ void pack_weights(const float* __restrict__ wih0, const float* __restrict__ whh0,
                             const float* __restrict__ wih1, const float* __restrict__ whh1,
                             half_t* __restrict__ wsB) {
  int idx = blockIdx.x * 256 + threadIdx.x;       // < 851,968
  int j    = idx & 7;
  int lane = (idx >> 3) & 63;
  int kc   = (idx >> 9) % 26;
  int sl   = (idx >> 9) / 26;                     // hg*8 + w
  int hg = sl >> 3, w = sl & 7;
  int c16 = lane & 15;
  int wr = (c16 & 3) * 256 + hg * 32 + w * 4 + (c16 >> 2);
  int kf = ((lane >> 4) << 3) + j;
  float v;
  if (kc < 10) { int kk = kc * 32 + kf;        v = (kk < 64)  ? wih0[wr * 64 + kk]  : whh0[wr * 256 + kk - 64]; }
  else         { int kk = (kc - 10) * 32 + kf; v = (kk < 256) ? wih1[wr * 256 + kk] : whh1[wr * 256 + kk - 256]; }
  wsB[idx] = (half_t)v;
}

__device__ __forceinline__ float sigm(float x)   { return 1.0f / (1.0f + __expf(-x)); }
__device__ __forceinline__ float tanh_f(float x) { return 1.0f - 2.0f / (__expf(2.0f * x) + 1.0f); }
__device__ __forceinline__ float wsum(float v) {
  #pragma unroll
  for (int m = 1; m < 64; m <<= 1) v += __shfl_xor(v, m, 64);
  return v;
}
// A-fragment from swizzled LDS tile (byte ^= (row&7)<<4; row = l15, k = kc*32 + l4*8 + j)
__device__ __forceinline__ f16x8 ldA(const char* base, int stride, int kc, int l15, int l4) {
  int byo = l15 * stride + kc * 64 + l4 * 16;
  byo ^= (l15 & 7) << 4;
  return *(const f16x8*)(base + byo);
}
// In-wave 4x4 transpose across quad lanes (verified r4/r5): a[r]=M[q][r] -> a[g]=M[g][q], q=lane&3
__device__ __forceinline__ void quad_transpose(float a[4], int lane) {
  float y0 = __shfl_xor(a[0], 1), y1 = __shfl_xor(a[1], 1),
        y2 = __shfl_xor(a[2], 1), y3 = __shfl_xor(a[3], 1);
  bool odd = (lane & 1);
  float c0v = odd ? y1 : a[0];
  float c1v = odd ? a[1] : y0;
  float c2v = odd ? y3 : a[2];
  float c3v = odd ? a[3] : y2;
  float z0 = __shfl_xor(c0v, 2), z1 = __shfl_xor(c1v, 2),
        z2 = __shfl_xor(c2v, 2), z3 = __shfl_xor(c3v, 2);
  bool hi = (lane & 2);
  a[0] = hi ? z2 : c0v;
  a[1] = hi ? z3 : c1v;
  a[2] = hi ? c2v : z0;
  a[3] = hi ? c3v : z1;
}

// Gather one partner region (wave w <-> partner w): 8 contiguous words per lane (64B line),
// unpack {h1,h2} into swizzled LDS tiles. Tag-in-word: no fences anywhere.
__device__ __forceinline__ void gather_stage(const u64* slotbase, u32 want, int w, int lane,
                                             char* H1, char* H2) {
  const u64* src = slotbase + (size_t)w * 512 + (lane >> 2) * 32 + (lane & 3) * 8;
  u64 v[8];
  for (;;) {
    bool ok = true;
    #pragma unroll
    for (int k = 0; k < 8; k++) {
      v[k] = __hip_atomic_load(&src[k], __ATOMIC_RELAXED, __HIP_MEMORY_SCOPE_AGENT);
      ok &= ((u32)v[k] == want);
    }
    if (ok) break;
    __builtin_amdgcn_s_sleep(2);
  }
  union { u16 us[8]; uint4 u4; } a1, a2;
  #pragma unroll
  for (int k = 0; k < 8; k++) { a1.us[k] = (u16)(v[k] >> 32); a2.us[k] = (u16)(v[k] >> 48); }
  int row = lane >> 2;
  int bo = row * 512 + (w * 32 + (lane & 3) * 8) * 2;
  bo ^= (row & 7) << 4;
  *(uint4*)(H1 + bo) = a1.u4;
  *(uint4*)(H2 + bo) = a2.u4;
}

// 256 blocks (32 bg x 8 hg; bid = hg*32+bg -> partners co-XCD) x 512 threads (8 waves).
// Block owns 16 batch rows x 32 units (both layers, 4 gates). Weights in VGPRs.
// One tagged-word exchange per step; cells lane-local via quad transpose; 2 barriers/step.
__global__ __launch_bounds__(512, 2)
void lstm_fused(const float* __restrict__ x,
                const float* __restrict__ bih0, const float* __restrict__ bhh0,
                const float* __restrict__ bih1, const float* __restrict__ bhh1,
                const float* __restrict__ gam, const float* __restrict__ bet,
                const float* __restrict__ headw, const float* __restrict__ headb,
                char* __restrict__ ws, float* __restrict__ out) {
  __shared__ __align__(16) char smem[18432];
  char* XT = smem;          // [16][64]  f16, stride 128B, swizzled
  char* H1 = smem + 2048;   // [16][256] f16, stride 512B, swizzled
  char* H2 = smem + 10240;  // [16][256] f16, stride 512B, swizzled

  const int tid = threadIdx.x;
  const int w = tid >> 6, lane = tid & 63;
  const int l15 = lane & 15, l4 = lane >> 4;
  const int q = lane & 3, s = (lane >> 2) & 3;
  const int crow = l4 * 4 + q;          // cell batch-row owned by this lane
  const int ul = w * 4 + s;             // block-local unit owned by this lane
  const int hg = blockIdx.x >> 5, bg = blockIdx.x & 31;
  const int xr = tid >> 5, xk = (tid & 31) * 2;   // x staging map

  const half_t* wsB = (const half_t*)ws;
  u64* ring = (u64*)(ws + RING_OFF);
  const int pubidx = hg * 512 + crow * 32 + ul;   // hg-major publish layout

  // ---- weights -> registers (104 VGPRs/lane) ----
  f16x8 W0[10], W1[16];
  { const f16x8* wp = (const f16x8*)wsB + (size_t)((hg * 8 + w) * 26) * 64 + lane;
    #pragma unroll
    for (int f = 0; f < 10; f++) W0[f] = wp[f * 64];
    #pragma unroll
    for (int f = 0; f < 16; f++) W1[f] = wp[(10 + f) * 64]; }

  float bv0[4], bv1[4];
  { int ug = hg * 32 + ul;
    #pragma unroll
    for (int g = 0; g < 4; g++) {
      bv0[g] = bih0[g * 256 + ug] + bhh0[g * 256 + ug];
      bv1[g] = bih1[g * 256 + ug] + bhh1[g * 256 + ug];
    } }
  float c0 = 0.f, c1 = 0.f;

  // ---- prologue: zero H1 (h1[-1]=0); stage x0; load x1 ----
  for (int i2 = tid; i2 < 2048; i2 += 512) ((u32*)H1)[i2] = 0;
  { float2 v = *(const float2*)(x + ((size_t)(bg * 16 + xr) * T_STEPS + 0) * 64 + xk);
    union { half_t h[2]; u32 u; } cv;
    cv.h[0] = (half_t)v.x; cv.h[1] = (half_t)v.y;
    int bo = xr * 128 + xk * 2; bo ^= (xr & 7) << 4;
    *(u32*)(XT + bo) = cv.u; }
  float2 xv = *(const float2*)(x + ((size_t)(bg * 16 + xr) * T_STEPS + 1) * 64 + xk);
  __syncthreads();

  // ---- MM0(0) -> h1[0]; publish tag 1 = {h1[0], h2[-1]=0} ----
  {
    f32x4 acc0 = {0.f, 0.f, 0.f, 0.f};
    acc0 = __builtin_amdgcn_mfma_f32_16x16x32_f16(ldA(XT, 128, 0, l15, l4), W0[0], acc0, 0, 0, 0);
    acc0 = __builtin_amdgcn_mfma_f32_16x16x32_f16(ldA(XT, 128, 1, l15, l4), W0[1], acc0, 0, 0, 0);
    #pragma unroll
    for (int kh = 0; kh < 8; kh++)
      acc0 = __builtin_amdgcn_mfma_f32_16x16x32_f16(ldA(H1, 512, kh, l15, l4), W0[kh + 2], acc0, 0, 0, 0);
    float g0[4] = {acc0[0], acc0[1], acc0[2], acc0[3]};
    quad_transpose(g0, lane);
    c0 = sigm(g0[1] + bv0[1]) * c0 + sigm(g0[0] + bv0[0]) * tanh_f(g0[2] + bv0[2]);
    float h1f = sigm(g0[3] + bv0[3]) * tanh_f(c0);
    union { half_t hf; u16 us; } cv; cv.hf = (half_t)h1f;
    u64* slotb = ring + ((size_t)(1 & (DSLOT - 1)) * NBG + bg) * (NHG * 512);
    u64 word = (u64)1u | ((u64)(u32)cv.us << 32);
    __hip_atomic_store(&slotb[pubidx], word, __ATOMIC_RELAXED, __HIP_MEMORY_SCOPE_AGENT);
    asm volatile("s_waitcnt vmcnt(0)" ::: "memory");
  }
  __syncthreads();  // all MM0 reads of XT/H1 done
  {
    u64* slotb = ring + ((size_t)(1 & (DSLOT - 1)) * NBG + bg) * (NHG * 512);
    gather_stage(slotb, 1u, w, lane, H1, H2);
    union { half_t h[2]; u32 u; } cv;
    cv.h[0] = (half_t)xv.x; cv.h[1] = (half_t)xv.y;
    int bo = xr * 128 + xk * 2; bo ^= (xr & 7) << 4;
    *(u32*)(XT + bo) = cv.u;
  }

  // ---- main loop: iter i has staged {h1[i], h2[i-1], x[i+1]} ----
  for (int i = 0; i < T_STEPS - 1; i++) {
    __syncthreads();  // B1: staging visible
    const bool have_x = (i + 2 < T_STEPS);
    if (have_x) xv = *(const float2*)(x + ((size_t)(bg * 16 + xr) * T_STEPS + (i + 2)) * 64 + xk);

    // MM0(i+1): [x[i+1] | h1[i]] @ W0^T ; MM1(i): [h1[i] | h2[i-1]] @ W1^T  (H1 read once)
    f32x4 acc0 = {0.f, 0.f, 0.f, 0.f}, acc1 = {0.f, 0.f, 0.f, 0.f};
    acc0 = __builtin_amdgcn_mfma_f32_16x16x32_f16(ldA(XT, 128, 0, l15, l4), W0[0], acc0, 0, 0, 0);
    acc0 = __builtin_amdgcn_mfma_f32_16x16x32_f16(ldA(XT, 128, 1, l15, l4), W0[1], acc0, 0, 0, 0);
    #pragma unroll
    for (int kh = 0; kh < 8; kh++) {
      f16x8 a = ldA(H1, 512, kh, l15, l4);
      acc0 = __builtin_amdgcn_mfma_f32_16x16x32_f16(a, W0[kh + 2], acc0, 0, 0, 0);
      acc1 = __builtin_amdgcn_mfma_f32_16x16x32_f16(a, W1[kh], acc1, 0, 0, 0);
    }
    #pragma unroll
    for (int kh = 0; kh < 8; kh++)
      acc1 = __builtin_amdgcn_mfma_f32_16x16x32_f16(ldA(H2, 512, kh, l15, l4), W1[kh + 8], acc1, 0, 0, 0);

    // cells (lane-local after quad transpose)
    float g0[4] = {acc0[0], acc0[1], acc0[2], acc0[3]};
    quad_transpose(g0, lane);
    c0 = sigm(g0[1] + bv0[1]) * c0 + sigm(g0[0] + bv0[0]) * tanh_f(g0[2] + bv0[2]);
    float h1f = sigm(g0[3] + bv0[3]) * tanh_f(c0);
    float g1[4] = {acc1[0], acc1[1], acc1[2], acc1[3]};
    quad_transpose(g1, lane);
    c1 = sigm(g1[1] + bv1[1]) * c1 + sigm(g1[0] + bv1[0]) * tanh_f(g1[2] + bv1[2]);
    float h2f = sigm(g1[3] + bv1[3]) * tanh_f(c1);

    // publish tag i+2 = {h1[i+1], h2[i]}
    const u32 tag = (u32)(i + 2);
    u64* slotb = ring + ((size_t)(tag & (DSLOT - 1)) * NBG + bg) * (NHG * 512);
    {
      union { half_t hf; u16 us; } cv1, cv2;
      cv1.hf = (half_t)h1f; cv2.hf = (half_t)h2f;
      u64 word = (u64)tag | ((u64)((u32)cv1.us | ((u32)cv2.us << 16)) << 32);
      __hip_atomic_store(&slotb[pubidx], word, __ATOMIC_RELAXED, __HIP_MEMORY_SCOPE_AGENT);
      asm volatile("s_waitcnt vmcnt(0)" ::: "memory");
    }
    __syncthreads();  // B2: all MM reads done; tiles may be overwritten

    gather_stage(slotb, tag, w, lane, H1, H2);
    if (have_x) {
      union { half_t h[2]; u32 u; } cv;
      cv.h[0] = (half_t)xv.x; cv.h[1] = (half_t)xv.y;
      int bo = xr * 128 + xk * 2; bo ^= (xr & 7) << 4;
      *(u32*)(XT + bo) = cv.u;
    }
  }

  // ---- epilogue: staged {h1[T-1], h2[T-2]}; MM1(T-1) -> h2[T-1]; publish f32 tag T+1 ----
  __syncthreads();
  {
    f32x4 acc1 = {0.f, 0.f, 0.f, 0.f};
    #pragma unroll
    for (int kh = 0; kh < 8; kh++)
      acc1 = __builtin_amdgcn_mfma_f32_16x16x32_f16(ldA(H1, 512, kh, l15, l4), W1[kh], acc1, 0, 0, 0);
    #pragma unroll
    for (int kh = 0; kh < 8; kh++)
      acc1 = __builtin_amdgcn_mfma_f32_16x16x32_f16(ldA(H2, 512, kh, l15, l4), W1[kh + 8], acc1, 0, 0, 0);
    float g1[4] = {acc1[0], acc1[1], acc1[2], acc1[3]};
    quad_transpose(g1, lane);
    c1 = sigm(g1[1] + bv1[1]) * c1 + sigm(g1[0] + bv1[0]) * tanh_f(g1[2] + bv1[2]);
    float h2f = sigm(g1[3] + bv1[3]) * tanh_f(c1);
    const u32 tagF = (u32)(T_STEPS + 1);
    u64* slotb = ring + ((size_t)(tagF & (DSLOT - 1)) * NBG + bg) * (NHG * 512);
    u64 word = (u64)tagF | ((u64)__float_as_uint(h2f) << 32);
    __hip_atomic_store(&slotb[pubidx], word, __ATOMIC_RELAXED, __HIP_MEMORY_SCOPE_AGENT);
    asm volatile("s_waitcnt vmcnt(0)" ::: "memory");
  }
  if (hg != 0) return;

  // ---- LN + exact GELU + head (hg==0 blocks, one per bg) ----
  __syncthreads();
  float* HF = (float*)smem;  // [16][256] f32 overlay (tiles dead)
  {
    const u32 want = (u32)(T_STEPS + 1);
    const u64* src = ring + ((size_t)(want & (DSLOT - 1)) * NBG + bg) * (NHG * 512)
                   + (size_t)w * 512 + (lane >> 2) * 32 + (lane & 3) * 8;
    u64 v[8];
    for (;;) {
      bool ok = true;
      #pragma unroll
      for (int k = 0; k < 8; k++) {
        v[k] = __hip_atomic_load(&src[k], __ATOMIC_RELAXED, __HIP_MEMORY_SCOPE_AGENT);
        ok &= ((u32)v[k] == want);
      }
      if (ok) break;
      __builtin_amdgcn_s_sleep(2);
    }
    #pragma unroll
    for (int k = 0; k < 8; k++)
      HF[(lane >> 2) * 256 + w * 32 + (lane & 3) * 8 + k] = __uint_as_float((u32)(v[k] >> 32));
  }
  __syncthreads();

  float hbv = headb[0];
  #pragma unroll
  for (int rj = 0; rj < 2; rj++) {
    int rr = w * 2 + rj;
    float vv[4], sm = 0.f;
    #pragma unroll
    for (int qq = 0; qq < 4; qq++) { vv[qq] = HF[rr * 256 + qq * 64 + lane]; sm += vv[qq]; }
    sm = wsum(sm);
    float mu = sm * (1.0f / 256.0f);
    float vs = 0.f;
    #pragma unroll
    for (int qq = 0; qq < 4; qq++) { float d = vv[qq] - mu; vs += d * d; }
    vs = wsum(vs);
    float rstd = rsqrtf(vs * (1.0f / 256.0f) + 1e-5f);
    float dot = 0.f;
    #pragma unroll
    for (int qq = 0; qq < 4; qq++) {
      int uu = qq * 64 + lane;
      float y = (vv[qq] - mu) * rstd * gam[uu] + bet[uu];
      float ge = 0.5f * y * (1.0f + erff(y * 0.70710678118f));
      dot += ge * headw[uu];
    }
    dot = wsum(dot);
    if (lane == 0) out[bg * 16 + rr] = dot + hbv;
  }
}

extern "C" void kernel_launch(void* const* d_in, const int* in_sizes, int n_in,
                              void* d_out, int out_size, void* d_ws, size_t ws_size,
                              hipStream_t stream) {
  const float* x    = (const float*)d_in[0];
  const float* wih0 = (const float*)d_in[1];
  const float* whh0 = (const float*)d_in[2];
  const float* bih0 = (const float*)d_in[3];
  const float* bhh0 = (const float*)d_in[4];
  const float* wih1 = (const float*)d_in[5];
  const float* whh1 = (const float*)d_in[6];
  const float* bih1 = (const float*)d_in[7];
  const float* bhh1 = (const float*)d_in[8];
  const float* gam  = (const float*)d_in[9];
  const float* bet  = (const float*)d_in[10];
  const float* hw   = (const float*)d_in[11];
  const float* hb   = (const float*)d_in[12];
  char* ws = (char*)d_ws;  // needs 3,801,088 bytes

  hipLaunchKernelGGL(init_ws, dim3((RING_WORDS * 2 + 1023) / 1024), dim3(1024), 0, stream,
                     (u32*)(ws + RING_OFF));
  hipLaunchKernelGGL(pack_weights, dim3(3328), dim3(256), 0, stream,
                     wih0, whh0, wih1, whh1, (half_t*)ws);
  hipLaunchKernelGGL(lstm_fused, dim3(256), dim3(512), 0, stream,
                     x, bih0, bhh0, bih1, bhh1, gam, bet, hw, hb, ws, (float*)d_out);
}